// Round 1
// baseline (428.405 us; speedup 1.0000x reference)
//
#include <hip/hip_runtime.h>
#include <hip/hip_bf16.h>
#include <cstdint>
#include <cstddef>

typedef __bf16 bf16_t;
typedef bf16_t bf16x8 __attribute__((ext_vector_type(8)));
typedef bf16_t bf16x4v __attribute__((ext_vector_type(4)));
typedef float floatx4 __attribute__((ext_vector_type(4)));

static constexpr int B_ = 8192;   // batch
static constexpr int H_ = 1024;   // hidden
static constexpr int G4 = 4096;   // 4*H
static constexpr int K_ = 1024;   // input size == hidden size

// ---- async global->LDS, 16B per lane. LDS dest must be wave-uniform base;
// HW adds lane*16. Int-cast trick (CK-style): low 32 bits of generic LDS
// pointer == AS(3) offset.
__device__ inline void async_copy16(const bf16_t* g, bf16_t* l) {
  auto l3 = (__attribute__((address_space(3))) void*)(uint32_t)(uintptr_t)l;
  __builtin_amdgcn_global_load_lds(
      (__attribute__((address_space(1))) void*)(uintptr_t)g, l3, 16, 0, 0);
}

// ---------------- cast fp32 -> bf16, 4 elems/thread ----------------
__global__ __launch_bounds__(256) void cast_f32_to_bf16(
    const float* __restrict__ src, bf16_t* __restrict__ dst, int n4) {
  int i = blockIdx.x * blockDim.x + threadIdx.x;
  if (i < n4) {
    const float4 v = ((const float4*)src)[i];
    bf16x4v o;
    o[0] = (bf16_t)v.x; o[1] = (bf16_t)v.y;
    o[2] = (bf16_t)v.z; o[3] = (bf16_t)v.w;
    ((bf16x4v*)dst)[i] = o;
  }
}

// ---------------- dual GEMM: C = A * W^T (both K-major), bf16 in/out ----------------
// m97 structure: 128x128 tile, BK=32, 4 waves (2x2), 4x4 16x16x32 MFMA per wave.
__global__ __launch_bounds__(256) void gemm_bt_dual(
    const bf16_t* __restrict__ A0, const bf16_t* __restrict__ A1,
    const bf16_t* __restrict__ W0, const bf16_t* __restrict__ W1,
    bf16_t* __restrict__ C0, bf16_t* __restrict__ C1) {
  constexpr int N = G4, K = K_;
  const bf16_t* A = blockIdx.z ? A1 : A0;
  const bf16_t* W = blockIdx.z ? W1 : W0;
  bf16_t*       C = blockIdx.z ? C1 : C0;

  __shared__ bf16_t As[128 * 32];
  __shared__ bf16_t Bs[128 * 32];

  const int tid  = threadIdx.x;
  const int lane = tid & 63;
  const int wid  = tid >> 6;
  const int wm   = wid >> 1, wn = wid & 1;
  const int lrow = lane & 15, quad = lane >> 4;

  const int m0 = blockIdx.y * 128;
  const int n0 = blockIdx.x * 128;

  // staging: 512 chunks of 16B (8 bf16). chunk L -> tile row L>>2, col8 (L&3)*8
  const int L0 = tid;
  const int L1 = 256 + tid;
  const bf16_t* gA0 = A + (size_t)(m0 + (L0 >> 2)) * K + (L0 & 3) * 8;
  const bf16_t* gA1 = A + (size_t)(m0 + (L1 >> 2)) * K + (L1 & 3) * 8;
  const bf16_t* gB0 = W + (size_t)(n0 + (L0 >> 2)) * K + (L0 & 3) * 8;
  const bf16_t* gB1 = W + (size_t)(n0 + (L1 >> 2)) * K + (L1 & 3) * 8;
  bf16_t* lA0 = As + wid * 512;          // wave-uniform LDS bases
  bf16_t* lA1 = As + 2048 + wid * 512;
  bf16_t* lB0 = Bs + wid * 512;
  bf16_t* lB1 = Bs + 2048 + wid * 512;

  floatx4 acc[4][4] = {};

  for (int k0 = 0; k0 < K; k0 += 32) {
    __syncthreads();                      // LDS reuse fence
    async_copy16(gA0 + k0, lA0);
    async_copy16(gA1 + k0, lA1);
    async_copy16(gB0 + k0, lB0);
    async_copy16(gB1 + k0, lB1);
    __syncthreads();                      // vmcnt(0) drain + barrier

    bf16x8 af[4], bfr[4];
#pragma unroll
    for (int i = 0; i < 4; ++i)
      af[i] = *(const bf16x8*)&As[(wm * 64 + i * 16 + lrow) * 32 + quad * 8];
#pragma unroll
    for (int j = 0; j < 4; ++j)
      bfr[j] = *(const bf16x8*)&Bs[(wn * 64 + j * 16 + lrow) * 32 + quad * 8];
#pragma unroll
    for (int i = 0; i < 4; ++i)
#pragma unroll
      for (int j = 0; j < 4; ++j)
        acc[i][j] = __builtin_amdgcn_mfma_f32_16x16x32_bf16(af[i], bfr[j],
                                                            acc[i][j], 0, 0, 0);
  }

  // C/D layout (m89-verified): col(n)=lane&15, row(m)=quad*4+reg
#pragma unroll
  for (int i = 0; i < 4; ++i) {
    const int mbase = m0 + wm * 64 + i * 16 + quad * 4;
#pragma unroll
    for (int j = 0; j < 4; ++j) {
      const int n = n0 + wn * 64 + j * 16 + lrow;
#pragma unroll
      for (int r = 0; r < 4; ++r)
        C[(size_t)(mbase + r) * N + n] = (bf16_t)acc[i][j][r];
    }
  }
}

// ---------------- fused LN(ig)+LN(hg) -> gates -> cell -> LN(c) -> hy,cy ----------------
__device__ inline float sigmoid_f(float x) { return 1.0f / (1.0f + __expf(-x)); }
__device__ inline float tanh_f(float x) {
  float e = __expf(2.0f * x);
  return 1.0f - 2.0f / (e + 1.0f);   // safe at +/-inf
}
__device__ inline int swz(int n) { return n + (n >> 4); }  // stride-17 LDS swizzle

__global__ __launch_bounds__(256) void ln_lstm_epilogue(
    const bf16_t* __restrict__ IG, const bf16_t* __restrict__ HG,
    const float* __restrict__ cx,
    const float* __restrict__ wi, const float* __restrict__ bi,
    const float* __restrict__ wh, const float* __restrict__ bh,
    const float* __restrict__ wc, const float* __restrict__ bc,
    float* __restrict__ hy_out, float* __restrict__ cy_out) {
  const int b = blockIdx.x;
  const int tid = threadIdx.x;
  const int lane = tid & 63;
  const int wid = tid >> 6;

  __shared__ float gates[4096 + 256];  // swizzled
  __shared__ float red[4][4];

  const bf16_t* ig = IG + (size_t)b * 4096;
  const bf16_t* hg = HG + (size_t)b * 4096;

  float vi[16], vh[16];
  {
    bf16x8 a0 = *(const bf16x8*)(ig + tid * 16);
    bf16x8 a1 = *(const bf16x8*)(ig + tid * 16 + 8);
    bf16x8 c0 = *(const bf16x8*)(hg + tid * 16);
    bf16x8 c1 = *(const bf16x8*)(hg + tid * 16 + 8);
#pragma unroll
    for (int e = 0; e < 8; ++e) {
      vi[e] = (float)a0[e]; vi[8 + e] = (float)a1[e];
      vh[e] = (float)c0[e]; vh[8 + e] = (float)c1[e];
    }
  }
  float si = 0, qi = 0, sh = 0, qh = 0;
#pragma unroll
  for (int k = 0; k < 16; ++k) {
    si += vi[k]; qi = fmaf(vi[k], vi[k], qi);
    sh += vh[k]; qh = fmaf(vh[k], vh[k], qh);
  }
#pragma unroll
  for (int off = 32; off; off >>= 1) {
    si += __shfl_down(si, off); qi += __shfl_down(qi, off);
    sh += __shfl_down(sh, off); qh += __shfl_down(qh, off);
  }
  if (lane == 0) { red[wid][0] = si; red[wid][1] = qi; red[wid][2] = sh; red[wid][3] = qh; }
  __syncthreads();
  si = red[0][0] + red[1][0] + red[2][0] + red[3][0];
  qi = red[0][1] + red[1][1] + red[2][1] + red[3][1];
  sh = red[0][2] + red[1][2] + red[2][2] + red[3][2];
  qh = red[0][3] + red[1][3] + red[2][3] + red[3][3];

  const float invN = 1.0f / 4096.0f;
  const float mui = si * invN, muh = sh * invN;
  const float rsi = rsqrtf(fmaxf(qi * invN - mui * mui, 0.0f) + 1e-5f);
  const float rsh = rsqrtf(fmaxf(qh * invN - muh * muh, 0.0f) + 1e-5f);

  // phase 2: normalized+affine gates -> swizzled LDS
#pragma unroll
  for (int k4 = 0; k4 < 4; ++k4) {
    const int nb = tid * 16 + k4 * 4;
    const float4 wiv = *(const float4*)(wi + nb);
    const float4 biv = *(const float4*)(bi + nb);
    const float4 whv = *(const float4*)(wh + nb);
    const float4 bhv = *(const float4*)(bh + nb);
    const float wia[4] = {wiv.x, wiv.y, wiv.z, wiv.w};
    const float bia[4] = {biv.x, biv.y, biv.z, biv.w};
    const float wha[4] = {whv.x, whv.y, whv.z, whv.w};
    const float bha[4] = {bhv.x, bhv.y, bhv.z, bhv.w};
#pragma unroll
    for (int j = 0; j < 4; ++j) {
      const int k = k4 * 4 + j;
      const float g = (vi[k] - mui) * rsi * wia[j] + bia[j] +
                      (vh[k] - muh) * rsh * wha[j] + bha[j];
      gates[swz(nb + j)] = g;
    }
  }
  __syncthreads();

  // phase 3: gate nonlinearities + cell update; thread t owns h = 4t..4t+3
  const float4 cx4 = *(const float4*)(cx + (size_t)b * 1024 + tid * 4);
  const float cxa[4] = {cx4.x, cx4.y, cx4.z, cx4.w};
  float cv[4], ov[4];
  float sc = 0, qc = 0;
#pragma unroll
  for (int j = 0; j < 4; ++j) {
    const int h = tid * 4 + j;
    const float in_g = sigmoid_f(gates[swz(h)]);
    const float fo_g = sigmoid_f(gates[swz(h + 1024)]);
    const float ce_g = tanh_f(gates[swz(h + 2048)]);
    ov[j] = sigmoid_f(gates[swz(h + 3072)]);
    const float c = fo_g * cxa[j] + in_g * ce_g;
    cv[j] = c;
    sc += c; qc = fmaf(c, c, qc);
  }
#pragma unroll
  for (int off = 32; off; off >>= 1) {
    sc += __shfl_down(sc, off); qc += __shfl_down(qc, off);
  }
  if (lane == 0) { red[wid][0] = sc; red[wid][1] = qc; }
  __syncthreads();
  sc = red[0][0] + red[1][0] + red[2][0] + red[3][0];
  qc = red[0][1] + red[1][1] + red[2][1] + red[3][1];
  const float invH = 1.0f / 1024.0f;
  const float muc = sc * invH;
  const float rsc = rsqrtf(fmaxf(qc * invH - muc * muc, 0.0f) + 1e-5f);

  const float4 wc4 = ((const float4*)wc)[tid];
  const float4 bc4 = ((const float4*)bc)[tid];
  const float wca[4] = {wc4.x, wc4.y, wc4.z, wc4.w};
  const float bca[4] = {bc4.x, bc4.y, bc4.z, bc4.w};
  float4 hyv, cyv;
  float cya[4], hya[4];
#pragma unroll
  for (int j = 0; j < 4; ++j) {
    const float cyn = (cv[j] - muc) * rsc * wca[j] + bca[j];
    cya[j] = cyn;
    hya[j] = ov[j] * tanh_f(cyn);
  }
  cyv.x = cya[0]; cyv.y = cya[1]; cyv.z = cya[2]; cyv.w = cya[3];
  hyv.x = hya[0]; hyv.y = hya[1]; hyv.z = hya[2]; hyv.w = hya[3];
  *(float4*)(cy_out + (size_t)b * 1024 + tid * 4) = cyv;
  *(float4*)(hy_out + (size_t)b * 1024 + tid * 4) = hyv;
}

extern "C" void kernel_launch(void* const* d_in, const int* in_sizes, int n_in,
                              void* d_out, int out_size, void* d_ws, size_t ws_size,
                              hipStream_t stream) {
  const float* input  = (const float*)d_in[0];
  const float* hx     = (const float*)d_in[1];
  const float* cx     = (const float*)d_in[2];
  const float* w_ih   = (const float*)d_in[3];
  const float* w_hh   = (const float*)d_in[4];
  const float* ln_i_w = (const float*)d_in[5];
  const float* ln_i_b = (const float*)d_in[6];
  const float* ln_h_w = (const float*)d_in[7];
  const float* ln_h_b = (const float*)d_in[8];
  const float* ln_c_w = (const float*)d_in[9];
  const float* ln_c_b = (const float*)d_in[10];

  float* out = (float*)d_out;
  float* hy = out;
  float* cy = out + (size_t)B_ * H_;

  // workspace layout (bf16): A 16MB | H 16MB | Wih 8MB | Whh 8MB | IG 64MB | HG 64MB = 176MB
  bf16_t* Abf = (bf16_t*)d_ws;
  bf16_t* Hbf = Abf + (size_t)B_ * K_;
  bf16_t* Wib = Hbf + (size_t)B_ * K_;
  bf16_t* Whb = Wib + (size_t)G4 * K_;
  bf16_t* IG  = Whb + (size_t)G4 * K_;
  bf16_t* HG  = IG + (size_t)B_ * G4;

  const int T = 256;
  cast_f32_to_bf16<<<(B_ * K_ / 4 + T - 1) / T, T, 0, stream>>>(input, Abf, B_ * K_ / 4);
  cast_f32_to_bf16<<<(B_ * K_ / 4 + T - 1) / T, T, 0, stream>>>(hx, Hbf, B_ * K_ / 4);
  cast_f32_to_bf16<<<(G4 * K_ / 4 + T - 1) / T, T, 0, stream>>>(w_ih, Wib, G4 * K_ / 4);
  cast_f32_to_bf16<<<(G4 * K_ / 4 + T - 1) / T, T, 0, stream>>>(w_hh, Whb, G4 * K_ / 4);

  gemm_bt_dual<<<dim3(G4 / 128, B_ / 128, 2), 256, 0, stream>>>(Abf, Hbf, Wib, Whb, IG, HG);

  ln_lstm_epilogue<<<B_, 256, 0, stream>>>(IG, HG, cx, ln_i_w, ln_i_b,
                                           ln_h_w, ln_h_b, ln_c_w, ln_c_b, hy, cy);
}

// Round 2
// 385.167 us; speedup vs baseline: 1.1123x; 1.1123x over previous
//
#include <hip/hip_runtime.h>
#include <hip/hip_bf16.h>
#include <cstdint>
#include <cstddef>

typedef __bf16 bf16_t;
typedef bf16_t bf16x8 __attribute__((ext_vector_type(8)));
typedef bf16_t bf16x4v __attribute__((ext_vector_type(4)));
typedef float floatx4 __attribute__((ext_vector_type(4)));

static constexpr int B_ = 8192;   // batch
static constexpr int H_ = 1024;   // hidden
static constexpr int G4 = 4096;   // 4*H
static constexpr int K_ = 1024;   // input size == hidden size

// ---- async global->LDS, 16B per lane (lane's dest = uniform base + lane*16)
__device__ inline void async_copy16(const bf16_t* g, bf16_t* l) {
  auto l3 = (__attribute__((address_space(3))) void*)(uint32_t)(uintptr_t)l;
  __builtin_amdgcn_global_load_lds(
      (__attribute__((address_space(1))) void*)(uintptr_t)g, l3, 16, 0, 0);
}

// ---------------- cast input+hx fp32 -> bf16, 8 elems/thread, one launch ----
__global__ __launch_bounds__(256) void cast2_f32_bf16(
    const float* __restrict__ a, const float* __restrict__ b,
    bf16_t* __restrict__ oa, bf16_t* __restrict__ ob, int n8each) {
  int gid = blockIdx.x * blockDim.x + threadIdx.x;
  const float* src; bf16_t* dst; int idx;
  if (gid < n8each) { src = a; dst = oa; idx = gid; }
  else              { src = b; dst = ob; idx = gid - n8each; }
  const float4 v0 = ((const float4*)src)[idx * 2];
  const float4 v1 = ((const float4*)src)[idx * 2 + 1];
  bf16x8 o;
  o[0] = (bf16_t)v0.x; o[1] = (bf16_t)v0.y; o[2] = (bf16_t)v0.z; o[3] = (bf16_t)v0.w;
  o[4] = (bf16_t)v1.x; o[5] = (bf16_t)v1.y; o[6] = (bf16_t)v1.z; o[7] = (bf16_t)v1.w;
  ((bf16x8*)dst)[idx] = o;
}

// ---- cast both weights fp32 -> bf16 with gate-interleaving row permutation.
// out row r' = h*4+g  <-  in row r = g*1024+h. One block per output row.
__global__ __launch_bounds__(256) void cast_w_perm(
    const float* __restrict__ wih, const float* __restrict__ whh,
    bf16_t* __restrict__ oih, bf16_t* __restrict__ ohh) {
  const int rp = blockIdx.x & 4095;            // output row within matrix
  const float* src = (blockIdx.x < 4096) ? wih : whh;
  bf16_t*      dst = (blockIdx.x < 4096) ? oih : ohh;
  const int h = rp >> 2, g = rp & 3;
  const int rin = g * 1024 + h;
  const int c = threadIdx.x * 4;
  const float4 v = *(const float4*)(src + (size_t)rin * K_ + c);
  bf16x4v o;
  o[0] = (bf16_t)v.x; o[1] = (bf16_t)v.y; o[2] = (bf16_t)v.z; o[3] = (bf16_t)v.w;
  *(bf16x4v*)(dst + (size_t)rp * K_ + c) = o;
}

// ---------------- dual GEMM: C = A * W^T (both K-major), bf16 in/out --------
// m97 structure: 128x128 tile, BK=32, 4 waves (2x2), 4x4 16x16x32 MFMA/wave.
__global__ __launch_bounds__(256) void gemm_bt_dual(
    const bf16_t* __restrict__ A0, const bf16_t* __restrict__ A1,
    const bf16_t* __restrict__ W0, const bf16_t* __restrict__ W1,
    bf16_t* __restrict__ C0, bf16_t* __restrict__ C1) {
  constexpr int N = G4, K = K_;
  const bf16_t* A = blockIdx.z ? A1 : A0;
  const bf16_t* W = blockIdx.z ? W1 : W0;
  bf16_t*       C = blockIdx.z ? C1 : C0;

  __shared__ bf16_t As[128 * 32];
  __shared__ bf16_t Bs[128 * 32];

  const int tid  = threadIdx.x;
  const int lane = tid & 63;
  const int wid  = tid >> 6;
  const int wm   = wid >> 1, wn = wid & 1;
  const int lrow = lane & 15, quad = lane >> 4;

  const int m0 = blockIdx.y * 128;
  const int n0 = blockIdx.x * 128;

  const int L0 = tid;
  const int L1 = 256 + tid;
  const bf16_t* gA0 = A + (size_t)(m0 + (L0 >> 2)) * K + (L0 & 3) * 8;
  const bf16_t* gA1 = A + (size_t)(m0 + (L1 >> 2)) * K + (L1 & 3) * 8;
  const bf16_t* gB0 = W + (size_t)(n0 + (L0 >> 2)) * K + (L0 & 3) * 8;
  const bf16_t* gB1 = W + (size_t)(n0 + (L1 >> 2)) * K + (L1 & 3) * 8;
  bf16_t* lA0 = As + wid * 512;
  bf16_t* lA1 = As + 2048 + wid * 512;
  bf16_t* lB0 = Bs + wid * 512;
  bf16_t* lB1 = Bs + 2048 + wid * 512;

  floatx4 acc[4][4] = {};

  for (int k0 = 0; k0 < K; k0 += 32) {
    __syncthreads();
    async_copy16(gA0 + k0, lA0);
    async_copy16(gA1 + k0, lA1);
    async_copy16(gB0 + k0, lB0);
    async_copy16(gB1 + k0, lB1);
    __syncthreads();

    bf16x8 af[4], bfr[4];
#pragma unroll
    for (int i = 0; i < 4; ++i)
      af[i] = *(const bf16x8*)&As[(wm * 64 + i * 16 + lrow) * 32 + quad * 8];
#pragma unroll
    for (int j = 0; j < 4; ++j)
      bfr[j] = *(const bf16x8*)&Bs[(wn * 64 + j * 16 + lrow) * 32 + quad * 8];
#pragma unroll
    for (int i = 0; i < 4; ++i)
#pragma unroll
      for (int j = 0; j < 4; ++j)
        acc[i][j] = __builtin_amdgcn_mfma_f32_16x16x32_bf16(af[i], bfr[j],
                                                            acc[i][j], 0, 0, 0);
  }

  // C/D layout (m89-verified): col(n)=lane&15, row(m)=quad*4+reg
#pragma unroll
  for (int i = 0; i < 4; ++i) {
    const int mbase = m0 + wm * 64 + i * 16 + quad * 4;
#pragma unroll
    for (int j = 0; j < 4; ++j) {
      const int n = n0 + wn * 64 + j * 16 + lrow;
#pragma unroll
      for (int r = 0; r < 4; ++r)
        C[(size_t)(mbase + r) * N + n] = (bf16_t)acc[i][j][r];
    }
  }
}

// ---------------- fused epilogue, gate-interleaved layout --------------------
// Thread t owns columns n' = 16t..16t+15 of its row = (h=4t+j, g=0..3).
// No gates-LDS roundtrip; 2 reduction barriers total.
__device__ inline float sigmoid_f(float x) { return 1.0f / (1.0f + __expf(-x)); }
__device__ inline float tanh_f(float x) {
  float e = __expf(2.0f * x);
  return 1.0f - 2.0f / (e + 1.0f);   // safe at +/-inf
}

__global__ __launch_bounds__(256) void ln_lstm_epilogue(
    const bf16_t* __restrict__ IG, const bf16_t* __restrict__ HG,
    const float* __restrict__ cx,
    const float* __restrict__ wi, const float* __restrict__ bi,
    const float* __restrict__ wh, const float* __restrict__ bh,
    const float* __restrict__ wc, const float* __restrict__ bc,
    float* __restrict__ hy_out, float* __restrict__ cy_out) {
  const int b = blockIdx.x;
  const int t = threadIdx.x;
  const int lane = t & 63;
  const int wid = t >> 6;

  __shared__ float red1[4][4];
  __shared__ float red2[4][2];

  // issue all global loads up front to overlap HBM latency
  const bf16x8 ig0 = *(const bf16x8*)(IG + (size_t)b * 4096 + t * 16);
  const bf16x8 ig1 = *(const bf16x8*)(IG + (size_t)b * 4096 + t * 16 + 8);
  const bf16x8 hg0 = *(const bf16x8*)(HG + (size_t)b * 4096 + t * 16);
  const bf16x8 hg1 = *(const bf16x8*)(HG + (size_t)b * 4096 + t * 16 + 8);
  const float4 cx4 = *(const float4*)(cx + (size_t)b * 1024 + t * 4);

  float vi[16], vh[16];
#pragma unroll
  for (int e = 0; e < 8; ++e) {
    vi[e] = (float)ig0[e]; vi[8 + e] = (float)ig1[e];
    vh[e] = (float)hg0[e]; vh[8 + e] = (float)hg1[e];
  }
  float si = 0, qi = 0, sh = 0, qh = 0;
#pragma unroll
  for (int k = 0; k < 16; ++k) {
    si += vi[k]; qi = fmaf(vi[k], vi[k], qi);
    sh += vh[k]; qh = fmaf(vh[k], vh[k], qh);
  }
#pragma unroll
  for (int off = 32; off; off >>= 1) {
    si += __shfl_down(si, off); qi += __shfl_down(qi, off);
    sh += __shfl_down(sh, off); qh += __shfl_down(qh, off);
  }
  if (lane == 0) { red1[wid][0] = si; red1[wid][1] = qi; red1[wid][2] = sh; red1[wid][3] = qh; }
  __syncthreads();
  si = red1[0][0] + red1[1][0] + red1[2][0] + red1[3][0];
  qi = red1[0][1] + red1[1][1] + red1[2][1] + red1[3][1];
  sh = red1[0][2] + red1[1][2] + red1[2][2] + red1[3][2];
  qh = red1[0][3] + red1[1][3] + red1[2][3] + red1[3][3];

  const float invN = 1.0f / 4096.0f;
  const float mui = si * invN, muh = sh * invN;
  const float rsi = rsqrtf(fmaxf(qi * invN - mui * mui, 0.0f) + 1e-5f);
  const float rsh = rsqrtf(fmaxf(qh * invN - muh * muh, 0.0f) + 1e-5f);

  // LN params in ORIGINAL layout: index g*1024 + h, h = 4t..4t+3 -> float4
  float4 wig[4], big[4], whg[4], bhg[4];
#pragma unroll
  for (int g = 0; g < 4; ++g) {
    wig[g] = *(const float4*)(wi + g * 1024 + t * 4);
    big[g] = *(const float4*)(bi + g * 1024 + t * 4);
    whg[g] = *(const float4*)(wh + g * 1024 + t * 4);
    bhg[g] = *(const float4*)(bh + g * 1024 + t * 4);
  }

  const float cxa[4] = {cx4.x, cx4.y, cx4.z, cx4.w};
  float cv[4], ov[4];
  float sc = 0, qc = 0;
#pragma unroll
  for (int j = 0; j < 4; ++j) {
    const float wg[4] = {((const float*)&wig[0])[j], ((const float*)&wig[1])[j],
                         ((const float*)&wig[2])[j], ((const float*)&wig[3])[j]};
    const float bg[4] = {((const float*)&big[0])[j], ((const float*)&big[1])[j],
                         ((const float*)&big[2])[j], ((const float*)&big[3])[j]};
    const float wg2[4] = {((const float*)&whg[0])[j], ((const float*)&whg[1])[j],
                          ((const float*)&whg[2])[j], ((const float*)&whg[3])[j]};
    const float bg2[4] = {((const float*)&bhg[0])[j], ((const float*)&bhg[1])[j],
                          ((const float*)&bhg[2])[j], ((const float*)&bhg[3])[j]};
    float G[4];
#pragma unroll
    for (int g = 0; g < 4; ++g) {
      const int e = j * 4 + g;   // n' = 16t + e  ->  h = 4t+j, gate g
      G[g] = (vi[e] - mui) * rsi * wg[g] + bg[g] +
             (vh[e] - muh) * rsh * wg2[g] + bg2[g];
    }
    const float in_g = sigmoid_f(G[0]);
    const float fo_g = sigmoid_f(G[1]);
    const float ce_g = tanh_f(G[2]);
    ov[j] = sigmoid_f(G[3]);
    const float c = fo_g * cxa[j] + in_g * ce_g;
    cv[j] = c;
    sc += c; qc = fmaf(c, c, qc);
  }
#pragma unroll
  for (int off = 32; off; off >>= 1) {
    sc += __shfl_down(sc, off); qc += __shfl_down(qc, off);
  }
  if (lane == 0) { red2[wid][0] = sc; red2[wid][1] = qc; }
  __syncthreads();
  sc = red2[0][0] + red2[1][0] + red2[2][0] + red2[3][0];
  qc = red2[0][1] + red2[1][1] + red2[2][1] + red2[3][1];
  const float invH = 1.0f / 1024.0f;
  const float muc = sc * invH;
  const float rsc = rsqrtf(fmaxf(qc * invH - muc * muc, 0.0f) + 1e-5f);

  const float4 wc4 = ((const float4*)wc)[t];
  const float4 bc4 = ((const float4*)bc)[t];
  const float wca[4] = {wc4.x, wc4.y, wc4.z, wc4.w};
  const float bca[4] = {bc4.x, bc4.y, bc4.z, bc4.w};
  float4 hyv, cyv;
#pragma unroll
  for (int j = 0; j < 4; ++j) {
    const float cyn = (cv[j] - muc) * rsc * wca[j] + bca[j];
    ((float*)&cyv)[j] = cyn;
    ((float*)&hyv)[j] = ov[j] * tanh_f(cyn);
  }
  *(float4*)(cy_out + (size_t)b * 1024 + t * 4) = cyv;
  *(float4*)(hy_out + (size_t)b * 1024 + t * 4) = hyv;
}

extern "C" void kernel_launch(void* const* d_in, const int* in_sizes, int n_in,
                              void* d_out, int out_size, void* d_ws, size_t ws_size,
                              hipStream_t stream) {
  const float* input  = (const float*)d_in[0];
  const float* hx     = (const float*)d_in[1];
  const float* cx     = (const float*)d_in[2];
  const float* w_ih   = (const float*)d_in[3];
  const float* w_hh   = (const float*)d_in[4];
  const float* ln_i_w = (const float*)d_in[5];
  const float* ln_i_b = (const float*)d_in[6];
  const float* ln_h_w = (const float*)d_in[7];
  const float* ln_h_b = (const float*)d_in[8];
  const float* ln_c_w = (const float*)d_in[9];
  const float* ln_c_b = (const float*)d_in[10];

  float* out = (float*)d_out;
  float* hy = out;
  float* cy = out + (size_t)B_ * H_;

  // workspace (bf16): A 16MB | H 16MB | Wih 8MB | Whh 8MB | IG 64MB | HG 64MB
  bf16_t* Abf = (bf16_t*)d_ws;
  bf16_t* Hbf = Abf + (size_t)B_ * K_;
  bf16_t* Wib = Hbf + (size_t)B_ * K_;
  bf16_t* Whb = Wib + (size_t)G4 * K_;
  bf16_t* IG  = Whb + (size_t)G4 * K_;
  bf16_t* HG  = IG + (size_t)B_ * G4;

  const int n8 = B_ * K_ / 8;  // 1M per tensor
  cast2_f32_bf16<<<(2 * n8) / 256, 256, 0, stream>>>(input, hx, Abf, Hbf, n8);
  cast_w_perm<<<2 * G4, 256, 0, stream>>>(w_ih, w_hh, Wib, Whb);

  gemm_bt_dual<<<dim3(G4 / 128, B_ / 128, 2), 256, 0, stream>>>(Abf, Hbf, Wib, Whb, IG, HG);

  ln_lstm_epilogue<<<B_, 256, 0, stream>>>(IG, HG, cx, ln_i_w, ln_i_b,
                                           ln_h_w, ln_h_b, ln_c_w, ln_c_b, hy, cy);
}

// Round 3
// 379.513 us; speedup vs baseline: 1.1288x; 1.0149x over previous
//
#include <hip/hip_runtime.h>
#include <hip/hip_bf16.h>
#include <cstdint>
#include <cstddef>

typedef __bf16 bf16_t;
typedef bf16_t bf16x8 __attribute__((ext_vector_type(8)));
typedef bf16_t bf16x4v __attribute__((ext_vector_type(4)));
typedef float floatx4 __attribute__((ext_vector_type(4)));

static constexpr int B_ = 8192;   // batch
static constexpr int H_ = 1024;   // hidden
static constexpr int G4 = 4096;   // 4*H
static constexpr int K_ = 1024;   // input size == hidden size

// ---- async global->LDS, 16B per lane (lane's dest = uniform base + lane*16)
__device__ inline void async_copy16(const bf16_t* g, bf16_t* l) {
  auto l3 = (__attribute__((address_space(3))) void*)(uint32_t)(uintptr_t)l;
  __builtin_amdgcn_global_load_lds(
      (__attribute__((address_space(1))) void*)(uintptr_t)g, l3, 16, 0, 0);
}

// ---------------- cast input+hx fp32 -> bf16, 8 elems/thread, one launch ----
__global__ __launch_bounds__(256) void cast2_f32_bf16(
    const float* __restrict__ a, const float* __restrict__ b,
    bf16_t* __restrict__ oa, bf16_t* __restrict__ ob, int n8each) {
  int gid = blockIdx.x * blockDim.x + threadIdx.x;
  const float* src; bf16_t* dst; int idx;
  if (gid < n8each) { src = a; dst = oa; idx = gid; }
  else              { src = b; dst = ob; idx = gid - n8each; }
  const float4 v0 = ((const float4*)src)[idx * 2];
  const float4 v1 = ((const float4*)src)[idx * 2 + 1];
  bf16x8 o;
  o[0] = (bf16_t)v0.x; o[1] = (bf16_t)v0.y; o[2] = (bf16_t)v0.z; o[3] = (bf16_t)v0.w;
  o[4] = (bf16_t)v1.x; o[5] = (bf16_t)v1.y; o[6] = (bf16_t)v1.z; o[7] = (bf16_t)v1.w;
  ((bf16x8*)dst)[idx] = o;
}

// ---- cast both weights fp32 -> bf16 with gate-interleaving row permutation.
// out row r' = h*4+g  <-  in row r = g*1024+h. One block per output row.
__global__ __launch_bounds__(256) void cast_w_perm(
    const float* __restrict__ wih, const float* __restrict__ whh,
    bf16_t* __restrict__ oih, bf16_t* __restrict__ ohh) {
  const int rp = blockIdx.x & 4095;            // output row within matrix
  const float* src = (blockIdx.x < 4096) ? wih : whh;
  bf16_t*      dst = (blockIdx.x < 4096) ? oih : ohh;
  const int h = rp >> 2, g = rp & 3;
  const int rin = g * 1024 + h;
  const int c = threadIdx.x * 4;
  const float4 v = *(const float4*)(src + (size_t)rin * K_ + c);
  bf16x4v o;
  o[0] = (bf16_t)v.x; o[1] = (bf16_t)v.y; o[2] = (bf16_t)v.z; o[3] = (bf16_t)v.w;
  *(bf16x4v*)(dst + (size_t)rp * K_ + c) = o;
}

// ---------------- dual GEMM: C = A * W^T (both K-major), bf16 in/out --------
// m97 structure: 128x128 tile, BK=32, 4 waves (2x2), 4x4 16x16x32 MFMA/wave.
// LDS XOR swizzle: tile chunk (row r, 16B-chunk c) lives at slot
// r*4 + (c ^ ((r>>1)&3)). Staging stays lane-contiguous (global_load_lds
// constraint); fragment reads spread each 16-lane phase over all 8
// bank-groups (2-way = free, vs 8-way = 2.94x before).
__global__ __launch_bounds__(256) void gemm_bt_dual(
    const bf16_t* __restrict__ A0, const bf16_t* __restrict__ A1,
    const bf16_t* __restrict__ W0, const bf16_t* __restrict__ W1,
    bf16_t* __restrict__ C0, bf16_t* __restrict__ C1) {
  constexpr int N = G4, K = K_;
  const bf16_t* A = blockIdx.z ? A1 : A0;
  const bf16_t* W = blockIdx.z ? W1 : W0;
  bf16_t*       C = blockIdx.z ? C1 : C0;

  __shared__ bf16_t As[128 * 32];
  __shared__ bf16_t Bs[128 * 32];

  const int tid  = threadIdx.x;
  const int lane = tid & 63;
  const int wid  = tid >> 6;
  const int wm   = wid >> 1, wn = wid & 1;
  const int lrow = lane & 15, quad = lane >> 4;

  const int m0 = blockIdx.y * 128;
  const int n0 = blockIdx.x * 128;

  // staging slots: slot L (16B) holds global chunk ((L&3) ^ ((L>>3)&3)) of row L>>2
  const int L0 = tid;
  const int L1 = 256 + tid;
  const int c0 = (((L0 & 3) ^ ((L0 >> 3) & 3))) * 8;
  const int c1 = (((L1 & 3) ^ ((L1 >> 3) & 3))) * 8;
  const bf16_t* gA0 = A + (size_t)(m0 + (L0 >> 2)) * K + c0;
  const bf16_t* gA1 = A + (size_t)(m0 + (L1 >> 2)) * K + c1;
  const bf16_t* gB0 = W + (size_t)(n0 + (L0 >> 2)) * K + c0;
  const bf16_t* gB1 = W + (size_t)(n0 + (L1 >> 2)) * K + c1;
  bf16_t* lA0 = As + wid * 512;
  bf16_t* lA1 = As + 2048 + wid * 512;
  bf16_t* lB0 = Bs + wid * 512;
  bf16_t* lB1 = Bs + 2048 + wid * 512;

  // fragment-read chunk after swizzle: quad ^ ((lrow>>1)&3)  (row base is ×16
  // so (r>>1)&3 == (lrow>>1)&3)
  const int qc = (quad ^ ((lrow >> 1) & 3)) * 8;

  floatx4 acc[4][4] = {};

  for (int k0 = 0; k0 < K; k0 += 32) {
    __syncthreads();
    async_copy16(gA0 + k0, lA0);
    async_copy16(gA1 + k0, lA1);
    async_copy16(gB0 + k0, lB0);
    async_copy16(gB1 + k0, lB1);
    __syncthreads();

    bf16x8 af[4], bfr[4];
#pragma unroll
    for (int i = 0; i < 4; ++i)
      af[i] = *(const bf16x8*)&As[(wm * 64 + i * 16 + lrow) * 32 + qc];
#pragma unroll
    for (int j = 0; j < 4; ++j)
      bfr[j] = *(const bf16x8*)&Bs[(wn * 64 + j * 16 + lrow) * 32 + qc];
#pragma unroll
    for (int i = 0; i < 4; ++i)
#pragma unroll
      for (int j = 0; j < 4; ++j)
        acc[i][j] = __builtin_amdgcn_mfma_f32_16x16x32_bf16(af[i], bfr[j],
                                                            acc[i][j], 0, 0, 0);
  }

  // C/D layout (m89-verified): col(n)=lane&15, row(m)=quad*4+reg
#pragma unroll
  for (int i = 0; i < 4; ++i) {
    const int mbase = m0 + wm * 64 + i * 16 + quad * 4;
#pragma unroll
    for (int j = 0; j < 4; ++j) {
      const int n = n0 + wn * 64 + j * 16 + lrow;
#pragma unroll
      for (int r = 0; r < 4; ++r)
        C[(size_t)(mbase + r) * N + n] = (bf16_t)acc[i][j][r];
    }
  }
}

// ---------------- fused epilogue, gate-interleaved layout --------------------
__device__ inline float sigmoid_f(float x) { return 1.0f / (1.0f + __expf(-x)); }
__device__ inline float tanh_f(float x) {
  float e = __expf(2.0f * x);
  return 1.0f - 2.0f / (e + 1.0f);   // safe at +/-inf
}

__global__ __launch_bounds__(256) void ln_lstm_epilogue(
    const bf16_t* __restrict__ IG, const bf16_t* __restrict__ HG,
    const float* __restrict__ cx,
    const float* __restrict__ wi, const float* __restrict__ bi,
    const float* __restrict__ wh, const float* __restrict__ bh,
    const float* __restrict__ wc, const float* __restrict__ bc,
    float* __restrict__ hy_out, float* __restrict__ cy_out) {
  const int b = blockIdx.x;
  const int t = threadIdx.x;
  const int lane = t & 63;
  const int wid = t >> 6;

  __shared__ float red1[4][4];
  __shared__ float red2[4][2];

  const bf16x8 ig0 = *(const bf16x8*)(IG + (size_t)b * 4096 + t * 16);
  const bf16x8 ig1 = *(const bf16x8*)(IG + (size_t)b * 4096 + t * 16 + 8);
  const bf16x8 hg0 = *(const bf16x8*)(HG + (size_t)b * 4096 + t * 16);
  const bf16x8 hg1 = *(const bf16x8*)(HG + (size_t)b * 4096 + t * 16 + 8);
  const float4 cx4 = *(const float4*)(cx + (size_t)b * 1024 + t * 4);

  float vi[16], vh[16];
#pragma unroll
  for (int e = 0; e < 8; ++e) {
    vi[e] = (float)ig0[e]; vi[8 + e] = (float)ig1[e];
    vh[e] = (float)hg0[e]; vh[8 + e] = (float)hg1[e];
  }
  float si = 0, qi = 0, sh = 0, qh = 0;
#pragma unroll
  for (int k = 0; k < 16; ++k) {
    si += vi[k]; qi = fmaf(vi[k], vi[k], qi);
    sh += vh[k]; qh = fmaf(vh[k], vh[k], qh);
  }
#pragma unroll
  for (int off = 32; off; off >>= 1) {
    si += __shfl_down(si, off); qi += __shfl_down(qi, off);
    sh += __shfl_down(sh, off); qh += __shfl_down(qh, off);
  }
  if (lane == 0) { red1[wid][0] = si; red1[wid][1] = qi; red1[wid][2] = sh; red1[wid][3] = qh; }
  __syncthreads();
  si = red1[0][0] + red1[1][0] + red1[2][0] + red1[3][0];
  qi = red1[0][1] + red1[1][1] + red1[2][1] + red1[3][1];
  sh = red1[0][2] + red1[1][2] + red1[2][2] + red1[3][2];
  qh = red1[0][3] + red1[1][3] + red1[2][3] + red1[3][3];

  const float invN = 1.0f / 4096.0f;
  const float mui = si * invN, muh = sh * invN;
  const float rsi = rsqrtf(fmaxf(qi * invN - mui * mui, 0.0f) + 1e-5f);
  const float rsh = rsqrtf(fmaxf(qh * invN - muh * muh, 0.0f) + 1e-5f);

  // LN params in ORIGINAL layout: index g*1024 + h, h = 4t..4t+3 -> float4
  float4 wig[4], big[4], whg[4], bhg[4];
#pragma unroll
  for (int g = 0; g < 4; ++g) {
    wig[g] = *(const float4*)(wi + g * 1024 + t * 4);
    big[g] = *(const float4*)(bi + g * 1024 + t * 4);
    whg[g] = *(const float4*)(wh + g * 1024 + t * 4);
    bhg[g] = *(const float4*)(bh + g * 1024 + t * 4);
  }

  const float cxa[4] = {cx4.x, cx4.y, cx4.z, cx4.w};
  float cv[4], ov[4];
  float sc = 0, qc2 = 0;
#pragma unroll
  for (int j = 0; j < 4; ++j) {
    const float wg[4] = {((const float*)&wig[0])[j], ((const float*)&wig[1])[j],
                         ((const float*)&wig[2])[j], ((const float*)&wig[3])[j]};
    const float bg[4] = {((const float*)&big[0])[j], ((const float*)&big[1])[j],
                         ((const float*)&big[2])[j], ((const float*)&big[3])[j]};
    const float wg2[4] = {((const float*)&whg[0])[j], ((const float*)&whg[1])[j],
                          ((const float*)&whg[2])[j], ((const float*)&whg[3])[j]};
    const float bg2[4] = {((const float*)&bhg[0])[j], ((const float*)&bhg[1])[j],
                          ((const float*)&bhg[2])[j], ((const float*)&bhg[3])[j]};
    float G[4];
#pragma unroll
    for (int g = 0; g < 4; ++g) {
      const int e = j * 4 + g;   // n' = 16t + e  ->  h = 4t+j, gate g
      G[g] = (vi[e] - mui) * rsi * wg[g] + bg[g] +
             (vh[e] - muh) * rsh * wg2[g] + bg2[g];
    }
    const float in_g = sigmoid_f(G[0]);
    const float fo_g = sigmoid_f(G[1]);
    const float ce_g = tanh_f(G[2]);
    ov[j] = sigmoid_f(G[3]);
    const float c = fo_g * cxa[j] + in_g * ce_g;
    cv[j] = c;
    sc += c; qc2 = fmaf(c, c, qc2);
  }
#pragma unroll
  for (int off = 32; off; off >>= 1) {
    sc += __shfl_down(sc, off); qc2 += __shfl_down(qc2, off);
  }
  if (lane == 0) { red2[wid][0] = sc; red2[wid][1] = qc2; }
  __syncthreads();
  sc = red2[0][0] + red2[1][0] + red2[2][0] + red2[3][0];
  qc2 = red2[0][1] + red2[1][1] + red2[2][1] + red2[3][1];
  const float invH = 1.0f / 1024.0f;
  const float muc = sc * invH;
  const float rsc = rsqrtf(fmaxf(qc2 * invH - muc * muc, 0.0f) + 1e-5f);

  const float4 wc4 = ((const float4*)wc)[t];
  const float4 bc4 = ((const float4*)bc)[t];
  const float wca[4] = {wc4.x, wc4.y, wc4.z, wc4.w};
  const float bca[4] = {bc4.x, bc4.y, bc4.z, bc4.w};
  float4 hyv, cyv;
#pragma unroll
  for (int j = 0; j < 4; ++j) {
    const float cyn = (cv[j] - muc) * rsc * wca[j] + bca[j];
    ((float*)&cyv)[j] = cyn;
    ((float*)&hyv)[j] = ov[j] * tanh_f(cyn);
  }
  *(float4*)(cy_out + (size_t)b * 1024 + t * 4) = cyv;
  *(float4*)(hy_out + (size_t)b * 1024 + t * 4) = hyv;
}

extern "C" void kernel_launch(void* const* d_in, const int* in_sizes, int n_in,
                              void* d_out, int out_size, void* d_ws, size_t ws_size,
                              hipStream_t stream) {
  const float* input  = (const float*)d_in[0];
  const float* hx     = (const float*)d_in[1];
  const float* cx     = (const float*)d_in[2];
  const float* w_ih   = (const float*)d_in[3];
  const float* w_hh   = (const float*)d_in[4];
  const float* ln_i_w = (const float*)d_in[5];
  const float* ln_i_b = (const float*)d_in[6];
  const float* ln_h_w = (const float*)d_in[7];
  const float* ln_h_b = (const float*)d_in[8];
  const float* ln_c_w = (const float*)d_in[9];
  const float* ln_c_b = (const float*)d_in[10];

  float* out = (float*)d_out;
  float* hy = out;
  float* cy = out + (size_t)B_ * H_;

  // workspace (bf16): A 16MB | H 16MB | Wih 8MB | Whh 8MB | IG 64MB | HG 64MB
  bf16_t* Abf = (bf16_t*)d_ws;
  bf16_t* Hbf = Abf + (size_t)B_ * K_;
  bf16_t* Wib = Hbf + (size_t)B_ * K_;
  bf16_t* Whb = Wib + (size_t)G4 * K_;
  bf16_t* IG  = Whb + (size_t)G4 * K_;
  bf16_t* HG  = IG + (size_t)B_ * G4;

  const int n8 = B_ * K_ / 8;  // 1M per tensor
  cast2_f32_bf16<<<(2 * n8) / 256, 256, 0, stream>>>(input, hx, Abf, Hbf, n8);
  cast_w_perm<<<2 * G4, 256, 0, stream>>>(w_ih, w_hh, Wib, Whb);

  gemm_bt_dual<<<dim3(G4 / 128, B_ / 128, 2), 256, 0, stream>>>(Abf, Hbf, Wib, Whb, IG, HG);

  ln_lstm_epilogue<<<B_, 256, 0, stream>>>(IG, HG, cx, ln_i_w, ln_i_b,
                                           ln_h_w, ln_h_b, ln_c_w, ln_c_b, hy, cy);
}